// Round 1
// baseline (170.447 us; speedup 1.0000x reference)
//
#include <hip/hip_runtime.h>
#include <math.h>

// ---------------- problem constants ----------------
#define KK     9     // corners
#define NCLS   13
#define NANC   5     // anchors
#define NBB    128
#define NHH    26
#define NWW    26
#define NTT    50    // targets
#define LL     21    // 2K+3
#define CHC    32    // 2K+1+NC channels per anchor
#define NPIX   676   // NH*NW
#define NANCHT 3380  // NA*NPIX
#define NCELLT 432640 // NB*NANCHT

// derived float constants (computed in double, rounded once)
#define LOG2E_F   1.4426950408889634f
#define K1C       2.8853900817779268f   // SHARP*log2e
#define K2C       0.036067376022224085f // K1C/TH
#define SXW       24.615384615384617f   // 640/26
#define SYH       18.461538461538463f   // 480/26
#define THRESH_S  43.500902934225507f   // 9 + SIL*9*(e^2-1)
#define CONF_T_SCALE 0.017390849194407297f // (1/(e^2-1))/9
#define OBJ_W     5.0f
#define EPOCH_PRETRAIN 15

static __device__ __forceinline__ float fast_exp2(float x){
#if __has_builtin(__builtin_amdgcn_exp2f)
  return __builtin_amdgcn_exp2f(x);
#else
  return exp2f(x);
#endif
}
static __device__ __forceinline__ float fast_sqrt(float x){
#if __has_builtin(__builtin_amdgcn_sqrtf)
  return __builtin_amdgcn_sqrtf(x);
#else
  return sqrtf(x);
#endif
}
static __device__ __forceinline__ float sigmoidf_(float x){
  return 1.0f/(1.0f + fast_exp2(-LOG2E_F*x));
}

__constant__ float c_anch[10] = {1.482f,2.2412f,2.0501f,3.1265f,2.3946f,4.6891f,
                                 3.1018f,3.991f,3.4879f,5.8851f};

// ws layout (bytes):
//   [0,4096)        : bc_part  double[NBB][4]   (loss_x, loss_y, loss_cls, conf_corr)
//   [4096,18432)    : partials double[1792]     (conf base, one per phaseA block)
//   [18432,479232)  : gts      float[NBB*NTT*18] scaled gt corners (px)
//   [479232,479744) : nvalid   int[NBB]
//   [479744,912384) : mask     u8[NCELLT]        conf_mask0 (0 or 1)

// ---------------- phase 0: prep scaled gt + valid counts ----------------
__global__ __launch_bounds__(128) void prep_kernel(const float* __restrict__ tgt,
                                                   float* __restrict__ gts,
                                                   int* __restrict__ nvalid){
  int b = blockIdx.x;
  const float* trow = tgt + (size_t)b*NTT*LL;
  for (int idx = threadIdx.x; idx < NTT*2*KK; idx += blockDim.x){
    int t = idx / (2*KK);
    int c = idx - t*(2*KK);             // 0..17 -> target col 1+c
    float v = trow[t*LL + 1 + c];
    float s = (c & 1) ? 480.0f : 640.0f;
    gts[((size_t)b*NTT + t)*(2*KK) + c] = v * s;
  }
  if (threadIdx.x == 0){
    int nv = 0;
    while (nv < NTT && trow[nv*LL + 1] != 0.0f) nv++;   // cumprod-valid is a prefix
    nvalid[b] = nv;
  }
}

// ---------------- phase A: cur_confs -> mask0, base conf loss ----------------
__global__ __launch_bounds__(256) void region_confmask_kernel(
    const float* __restrict__ outp, const float* __restrict__ gts,
    const int* __restrict__ nvalid, unsigned char* __restrict__ mask,
    double* __restrict__ partials){
  int b = blockIdx.y;
  int cell = blockIdx.x * blockDim.x + threadIdx.x;   // 0..3379 within batch
  float contrib = 0.0f;
  if (cell < NANCHT){
    int a   = cell / NPIX;
    int rem = cell - a*NPIX;
    int j   = rem / NWW;
    int i   = rem - j*NWW;
    const float* base = outp + (((size_t)b*NANC + a)*CHC)*NPIX + rem;

    float Px[KK], Py[KK];
#pragma unroll
    for (int k = 0; k < KK; ++k){
      float rx = base[(2*k)*NPIX];
      float ry = base[(2*k+1)*NPIX];
      if (k == 0){ rx = sigmoidf_(rx); ry = sigmoidf_(ry); }
      Px[k] = (rx + (float)i) * SXW;   // pred corner in pixels
      Py[k] = (ry + (float)j) * SYH;
    }

    int nv = nvalid[b];                       // wave-uniform -> SGPR
    const float* g = gts + (size_t)b*NTT*(2*KK);  // uniform addr -> s_load
    float cur = 9.0f;                         // == conf 0 in s-domain
    for (int t = 0; t < nv; ++t, g += 2*KK){
      float s = 0.0f;
#pragma unroll
      for (int k = 0; k < KK; ++k){
        float dx = Px[k] - g[2*k];
        float dy = Py[k] - g[2*k+1];
        float d  = fast_sqrt(fmaf(dy, dy, dx*dx));
        float e  = fast_exp2(fmaf(d, -K2C, K1C));
        s += fmaxf(e, 1.0f);                 // = (exp term clipped at d=TH) + 1
      }
      cur = fmaxf(cur, s);
    }
    int m0 = (cur > THRESH_S) ? 0 : 1;       // conf_mask0 (NOOBJ=1)
    mask[(size_t)b*NANCHT + cell] = (unsigned char)m0;
    float cf = sigmoidf_(base[(2*KK)*NPIX]);
    contrib = m0 ? 0.5f*cf*cf : 0.0f;        // base loss_conf (tconf=0 here)
  }
  // block reduce -> one double partial per block (deterministic, no atomics)
#pragma unroll
  for (int o = 32; o > 0; o >>= 1) contrib += __shfl_xor(contrib, o, 64);
  __shared__ float wsum[4];
  int wid = threadIdx.x >> 6, lane = threadIdx.x & 63;
  if (lane == 0) wsum[wid] = contrib;
  __syncthreads();
  if (threadIdx.x == 0){
    double tot = (double)wsum[0] + (double)wsum[1] + (double)wsum[2] + (double)wsum[3];
    partials[blockIdx.y * gridDim.x + blockIdx.x] = tot;
  }
}

// ---------------- phase B+C: per-target values, scatter winners, small losses ----------------
__global__ __launch_bounds__(64) void scatter_loss_kernel(
    const float* __restrict__ outp, const float* __restrict__ tgt,
    const float* __restrict__ gts, const int* __restrict__ nvalid,
    const unsigned char* __restrict__ mask, double* __restrict__ bc_part){
  int b = blockIdx.x;
  int t = threadIdx.x;                  // 0..63, targets are 0..49
  __shared__ int keys[NTT];
  int nv = nvalid[b];
  bool valid = (t < nv);

  int key = -1, gi0 = 0, gj0 = 0, bn = 0;
  float txv[KK], tyv[KK];
  float conf_t = 0.0f, tcls = 0.0f;

  if (t < NTT){
    const float* trow = tgt + ((size_t)b*NTT + t)*LL;
    tcls = trow[0];
    float gx0 = trow[1]*(float)NWW;
    float gy0 = trow[2]*(float)NHH;
    gi0 = min(max((int)floorf(gx0), 0), NWW-1);
    gj0 = min(max((int)floorf(gy0), 0), NHH-1);
#pragma unroll
    for (int k = 0; k < KK; ++k){
      txv[k] = trow[1+2*k]*(float)NWW - (float)gi0;
      tyv[k] = trow[2+2*k]*(float)NHH - (float)gj0;
    }
    // best anchor by IoU (first max wins)
    float gw = trow[LL-2]*(float)NWW, gh = trow[LL-1]*(float)NHH;
    float best = -1.0f;
    for (int a = 0; a < NANC; ++a){
      float aw = c_anch[2*a], ah = c_anch[2*a+1];
      float inter = fminf(aw, gw) * fminf(ah, gh);
      float iou = inter / (aw*ah + gw*gh - inter);
      if (iou > best){ best = iou; bn = a; }
    }
    key = bn*NPIX + gj0*NWW + gi0;
    keys[t] = key;

    // conf_t from pred_box at the wrapped flat index (reference's mod arithmetic)
    long f = (long)b*NANCHT - NPIX + gj0*NWW + gi0;
    if (f < 0) f += NCELLT;
    int bb  = (int)(f / NANCHT);
    int rr  = (int)(f - (long)bb*NANCHT);
    int aa  = rr / NPIX;
    int rr2 = rr - aa*NPIX;
    int jj  = rr2 / NWW;
    int ii  = rr2 - jj*NWW;
    const float* pbase = outp + (((size_t)bb*NANC + aa)*CHC)*NPIX + rr2;
    const float* g = gts + ((size_t)b*NTT + t)*(2*KK);
    float s = 0.0f;
#pragma unroll
    for (int k = 0; k < KK; ++k){
      float rx = pbase[(2*k)*NPIX], ry = pbase[(2*k+1)*NPIX];
      if (k == 0){ rx = sigmoidf_(rx); ry = sigmoidf_(ry); }
      float Pxx = (rx + (float)ii)*SXW, Pyy = (ry + (float)jj)*SYH;
      float dx = Pxx - g[2*k], dy = Pyy - g[2*k+1];
      float d  = fast_sqrt(fmaf(dy, dy, dx*dx));
      float e  = fast_exp2(fmaf(d, -K2C, K1C));
      s += fmaxf(e, 1.0f);
    }
    conf_t = (s - 9.0f) * CONF_T_SCALE;
  }
  __syncthreads();

  // winner = last valid t writing this (bn,gj,gi) cell (scan overwrite semantics)
  bool winner = valid;
  if (valid){
    for (int u = t+1; u < nv; ++u) if (keys[u] == key){ winner = false; break; }
  }

  double lx = 0.0, ly = 0.0, lcls = 0.0, lcf = 0.0;
  if (winner){
    const float* cbase = outp + (((size_t)b*NANC + bn)*CHC)*NPIX + gj0*NWW + gi0;
    float sx = 0.0f, sy = 0.0f;
#pragma unroll
    for (int k = 0; k < KK; ++k){
      float rx = cbase[(2*k)*NPIX], ry = cbase[(2*k+1)*NPIX];
      if (k == 0){ rx = sigmoidf_(rx); ry = sigmoidf_(ry); }
      float dx = rx - txv[k], dy = ry - tyv[k];
      sx = fmaf(dx, dx, sx); sy = fmaf(dy, dy, sy);
    }
    lx = 0.5*(double)sx; ly = 0.5*(double)sy;

    // class CE (log_softmax over 13 logits)
    float lg[NCLS], mx = -1e30f;
#pragma unroll
    for (int c = 0; c < NCLS; ++c){ lg[c] = cbase[(2*KK+1+c)*NPIX]; mx = fmaxf(mx, lg[c]); }
    float se = 0.0f;
#pragma unroll
    for (int c = 0; c < NCLS; ++c) se += fast_exp2((lg[c]-mx)*LOG2E_F);
    int label = min(max((int)tcls, 0), NCLS-1);
    lcls = (double)(mx + logf(se) - lg[label]);

    // conf-loss correction at object cell: + 0.5*OBJ*(conf-conf_t)^2 - base term
    float cf = sigmoidf_(cbase[(2*KK)*NPIX]);
    int m0 = mask[(size_t)b*NANCHT + (size_t)bn*NPIX + gj0*NWW + gi0];
    float dcf = cf - conf_t;
    lcf = 0.5*OBJ_W*(double)(dcf*dcf) - (m0 ? 0.5*(double)(cf*cf) : 0.0);
  }

  // single-wave block: shfl reduce doubles, write per-batch partials
#pragma unroll
  for (int o = 32; o > 0; o >>= 1){
    lx  += __shfl_xor(lx,  o, 64);
    ly  += __shfl_xor(ly,  o, 64);
    lcls+= __shfl_xor(lcls,o, 64);
    lcf += __shfl_xor(lcf, o, 64);
  }
  if (threadIdx.x == 0){
    double* bp = bc_part + (size_t)b*4;
    bp[0] = lx; bp[1] = ly; bp[2] = lcls; bp[3] = lcf;
  }
}

// ---------------- finalize: deterministic reduce + epoch gate ----------------
__global__ __launch_bounds__(256) void finalize_kernel(
    const double* __restrict__ bc_part, const double* __restrict__ partials,
    const int* __restrict__ epoch_p, float* __restrict__ outv){
  int tid = threadIdx.x;
  double vx=0, vy=0, vc=0, vf=0, vb=0;
  for (int i = tid; i < NBB; i += 256){
    vx += bc_part[4*i]; vy += bc_part[4*i+1];
    vc += bc_part[4*i+2]; vf += bc_part[4*i+3];
  }
  for (int i = tid; i < 14*NBB; i += 256) vb += partials[i];
#pragma unroll
  for (int o = 32; o > 0; o >>= 1){
    vx += __shfl_xor(vx, o, 64); vy += __shfl_xor(vy, o, 64);
    vc += __shfl_xor(vc, o, 64); vf += __shfl_xor(vf, o, 64);
    vb += __shfl_xor(vb, o, 64);
  }
  __shared__ double sm[5][4];
  int wid = tid >> 6, lane = tid & 63;
  if (lane == 0){ sm[0][wid]=vx; sm[1][wid]=vy; sm[2][wid]=vc; sm[3][wid]=vf; sm[4][wid]=vb; }
  __syncthreads();
  if (tid == 0){
    double fx=0, fy=0, fc=0, ff=0, fb=0;
    for (int w = 0; w < 4; ++w){ fx+=sm[0][w]; fy+=sm[1][w]; fc+=sm[2][w]; ff+=sm[3][w]; fb+=sm[4][w]; }
    double loss = fx + fy + fc;
    if (*epoch_p > EPOCH_PRETRAIN) loss += ff + fb;
    outv[0] = (float)loss;
  }
}

extern "C" void kernel_launch(void* const* d_in, const int* in_sizes, int n_in,
                              void* d_out, int out_size, void* d_ws, size_t ws_size,
                              hipStream_t stream){
  (void)in_sizes; (void)n_in; (void)out_size; (void)ws_size;
  const float* outp = (const float*)d_in[0];
  const float* tgt  = (const float*)d_in[1];
  const int*   ep   = (const int*)d_in[2];
  float* outv = (float*)d_out;
  char* ws = (char*)d_ws;

  double* bc_part  = (double*)(ws);                 // 4096 B
  double* partials = (double*)(ws + 4096);          // 14336 B
  float*  gts      = (float*) (ws + 18432);         // 460800 B
  int*    nvalid   = (int*)   (ws + 479232);        // 512 B
  unsigned char* mask = (unsigned char*)(ws + 479744); // 432640 B

  prep_kernel<<<dim3(NBB), dim3(128), 0, stream>>>(tgt, gts, nvalid);
  region_confmask_kernel<<<dim3(14, NBB), dim3(256), 0, stream>>>(outp, gts, nvalid, mask, partials);
  scatter_loss_kernel<<<dim3(NBB), dim3(64), 0, stream>>>(outp, tgt, gts, nvalid, mask, bc_part);
  finalize_kernel<<<dim3(1), dim3(256), 0, stream>>>(bc_part, partials, ep, outv);
}

// Round 2
// 142.593 us; speedup vs baseline: 1.1953x; 1.1953x over previous
//
#include <hip/hip_runtime.h>
#include <math.h>

// ---------------- problem constants ----------------
#define KK     9     // corners
#define NCLS   13
#define NANC   5     // anchors
#define NBB    128
#define NHH    26
#define NWW    26
#define NTT    50    // targets
#define LL     21    // 2K+3
#define CHC    32    // 2K+1+NC channels per anchor
#define NPIX   676   // NH*NW
#define NANCHT 3380  // NA*NPIX
#define NCELLT 432640 // NB*NANCHT

// derived float constants (computed in double, rounded once)
#define LOG2E_F   1.4426950408889634f
#define K1C       2.8853900817779268f   // SHARP*log2e
#define K2C       0.036067376022224085f // K1C/TH
#define SXW       24.615384615384617f   // 640/26
#define SYH       18.461538461538463f   // 480/26
#define THRESH_S  43.500902934225507f   // 9 + SIL*9*(e^2-1)
#define CULL_T2   292.0f                // > d*^2 = 288.25 where 9*e(d*) == THRESH_S
#define CONF_T_SCALE 0.017390849194407297f // (1/(e^2-1))/9
#define OBJ_W     5.0f
#define EPOCH_PRETRAIN 15

typedef __attribute__((ext_vector_type(2))) float f2;

static __device__ __forceinline__ float fast_exp2(float x){
#if __has_builtin(__builtin_amdgcn_exp2f)
  return __builtin_amdgcn_exp2f(x);
#else
  return exp2f(x);
#endif
}
static __device__ __forceinline__ float fast_sqrt(float x){
#if __has_builtin(__builtin_amdgcn_sqrtf)
  return __builtin_amdgcn_sqrtf(x);
#else
  return sqrtf(x);
#endif
}
static __device__ __forceinline__ float sigmoidf_(float x){
  return 1.0f/(1.0f + fast_exp2(-LOG2E_F*x));
}

__constant__ float c_anch[10] = {1.482f,2.2412f,2.0501f,3.1265f,2.3946f,4.6891f,
                                 3.1018f,3.991f,3.4879f,5.8851f};

// ws layout (bytes):
//   [0,4096)        : bc_part  double[NBB][4]
//   [4096,18432)    : partials double[1792]
//   [18432,479232)  : gts_neg  float[NBB*NTT*18]  NEGATED scaled gt corners (px)
//   [479232,479744) : nvalid   int[NBB]
//   [479744,912384) : mask     u8[NCELLT]

// ---------------- phase 0: prep (parallel nv via ballot; negate+scale gt) ----------------
__global__ __launch_bounds__(64) void prep_kernel(const float* __restrict__ tgt,
                                                  float* __restrict__ gts_neg,
                                                  int* __restrict__ nvalid){
  int b = blockIdx.x;
  int t = threadIdx.x;                          // one wave
  const float* trow = tgt + (size_t)b*NTT*LL;
  float v1 = (t < NTT) ? trow[t*LL + 1] : 0.0f;
  unsigned long long mk = __ballot(t < NTT && v1 != 0.0f);
  int firstInvalid = __ffsll(~mk) - 1;          // prefix length (cumprod semantics)
  if (t == 0) nvalid[b] = firstInvalid;
  for (int idx = t; idx < NTT*2*KK; idx += 64){
    int tt = idx / (2*KK);
    int c  = idx - tt*(2*KK);
    float v = trow[tt*LL + 1 + c];
    float s = (c & 1) ? 480.0f : 640.0f;
    gts_neg[((size_t)b*NTT + tt)*(2*KK) + c] = -(v * s);
  }
}

// ---------------- phase A: mask0 via cull + rare exact path; base conf loss ----------------
__global__ __launch_bounds__(256) void region_confmask_kernel(
    const float* __restrict__ outp, const float* __restrict__ gts_neg,
    const int* __restrict__ nvalid, unsigned char* __restrict__ mask,
    double* __restrict__ partials){
  int b = blockIdx.y;
  int cell = blockIdx.x * blockDim.x + threadIdx.x;   // 0..3379 within batch
  float contrib = 0.0f;
  if (cell < NANCHT){
    int a   = cell / NPIX;
    int rem = cell - a*NPIX;
    int j   = rem / NWW;
    int i   = rem - j*NWW;
    const float* base = outp + (((size_t)b*NANC + a)*CHC)*NPIX + rem;

    f2 P[KK];
#pragma unroll
    for (int k = 0; k < KK; ++k){
      float rx = base[(2*k)*NPIX];
      float ry = base[(2*k+1)*NPIX];
      if (k == 0){ rx = sigmoidf_(rx); ry = sigmoidf_(ry); }
      P[k].x = (rx + (float)i) * SXW;
      P[k].y = (ry + (float)j) * SYH;
    }

    int nv = nvalid[b];                           // wave-uniform -> SGPR
    const float* g = gts_neg + (size_t)b*NTT*(2*KK);  // uniform addr -> s_load
    unsigned long long qbits = 0ull;
    for (int t = 0; t < nv; ++t, g += 2*KK){
      float m = 1e30f;
#pragma unroll
      for (int k = 0; k < KK; ++k){
        f2 gv; gv.x = g[2*k]; gv.y = g[2*k+1];    // uniform scalars
        f2 d  = P[k] + gv;                        // pk_add (gt pre-negated)
        f2 sq = d * d;                            // pk_mul
        m = fminf(m, sq.x + sq.y);
      }
      if (m < CULL_T2) qbits |= (1ull << t);
    }

    int m0 = 1;
    if (__any(qbits != 0ull)){                    // rare exact path
      bool exc = false;
      while (qbits){
        int t = __ffsll((long long)qbits) - 1;
        qbits &= qbits - 1;
        const float* gg = gts_neg + ((size_t)b*NTT + t)*(2*KK);
        float s = 0.0f;
#pragma unroll
        for (int k = 0; k < KK; ++k){
          float dx = P[k].x + gg[2*k];
          float dy = P[k].y + gg[2*k+1];
          float d  = fast_sqrt(fmaf(dy, dy, dx*dx));   // identical to R0 math
          float e  = fast_exp2(fmaf(d, -K2C, K1C));
          s += fmaxf(e, 1.0f);
        }
        exc |= (s > THRESH_S);
      }
      if (exc) m0 = 0;
    }
    mask[(size_t)b*NANCHT + cell] = (unsigned char)m0;
    float cf = sigmoidf_(base[(2*KK)*NPIX]);
    contrib = m0 ? 0.5f*cf*cf : 0.0f;
  }
  // block reduce -> one double partial per block (deterministic, no atomics)
#pragma unroll
  for (int o = 32; o > 0; o >>= 1) contrib += __shfl_xor(contrib, o, 64);
  __shared__ float wsum[4];
  int wid = threadIdx.x >> 6, lane = threadIdx.x & 63;
  if (lane == 0) wsum[wid] = contrib;
  __syncthreads();
  if (threadIdx.x == 0){
    double tot = (double)wsum[0] + (double)wsum[1] + (double)wsum[2] + (double)wsum[3];
    partials[blockIdx.y * gridDim.x + blockIdx.x] = tot;
  }
}

// ---------------- phase B+C: per-target values, scatter winners, small losses ----------------
__global__ __launch_bounds__(64) void scatter_loss_kernel(
    const float* __restrict__ outp, const float* __restrict__ tgt,
    const int* __restrict__ nvalid, const unsigned char* __restrict__ mask,
    double* __restrict__ bc_part){
  int b = blockIdx.x;
  int t = threadIdx.x;                  // 0..63, targets are 0..49
  __shared__ int keys[NTT];
  int nv = nvalid[b];
  bool valid = (t < nv);

  int key = -1, gi0 = 0, gj0 = 0, bn = 0;
  float txv[KK], tyv[KK];
  float conf_t = 0.0f, tcls = 0.0f;

  if (t < NTT){
    const float* trow = tgt + ((size_t)b*NTT + t)*LL;
    tcls = trow[0];
    float gx0 = trow[1]*(float)NWW;
    float gy0 = trow[2]*(float)NHH;
    gi0 = min(max((int)floorf(gx0), 0), NWW-1);
    gj0 = min(max((int)floorf(gy0), 0), NHH-1);
#pragma unroll
    for (int k = 0; k < KK; ++k){
      txv[k] = trow[1+2*k]*(float)NWW - (float)gi0;
      tyv[k] = trow[2+2*k]*(float)NHH - (float)gj0;
    }
    // best anchor by IoU (first max wins)
    float gw = trow[LL-2]*(float)NWW, gh = trow[LL-1]*(float)NHH;
    float best = -1.0f;
    for (int a = 0; a < NANC; ++a){
      float aw = c_anch[2*a], ah = c_anch[2*a+1];
      float inter = fminf(aw, gw) * fminf(ah, gh);
      float iou = inter / (aw*ah + gw*gh - inter);
      if (iou > best){ best = iou; bn = a; }
    }
    key = bn*NPIX + gj0*NWW + gi0;
    keys[t] = key;

    // conf_t from pred_box at the wrapped flat index (reference's mod arithmetic)
    long f = (long)b*NANCHT - NPIX + gj0*NWW + gi0;
    if (f < 0) f += NCELLT;
    int bb  = (int)(f / NANCHT);
    int rr  = (int)(f - (long)bb*NANCHT);
    int aa  = rr / NPIX;
    int rr2 = rr - aa*NPIX;
    int jj  = rr2 / NWW;
    int ii  = rr2 - jj*NWW;
    const float* pbase = outp + (((size_t)bb*NANC + aa)*CHC)*NPIX + rr2;
    float s = 0.0f;
#pragma unroll
    for (int k = 0; k < KK; ++k){
      float rx = pbase[(2*k)*NPIX], ry = pbase[(2*k+1)*NPIX];
      if (k == 0){ rx = sigmoidf_(rx); ry = sigmoidf_(ry); }
      float Pxx = (rx + (float)ii)*SXW, Pyy = (ry + (float)jj)*SYH;
      float dx = Pxx - trow[1+2*k]*640.0f;
      float dy = Pyy - trow[2+2*k]*480.0f;
      float d  = fast_sqrt(fmaf(dy, dy, dx*dx));
      float e  = fast_exp2(fmaf(d, -K2C, K1C));
      s += fmaxf(e, 1.0f);
    }
    conf_t = (s - 9.0f) * CONF_T_SCALE;
  }
  __syncthreads();

  // winner = last valid t writing this (bn,gj,gi) cell (scan overwrite semantics)
  bool winner = valid;
  if (valid){
    for (int u = t+1; u < nv; ++u) if (keys[u] == key){ winner = false; break; }
  }

  double lx = 0.0, ly = 0.0, lcls = 0.0, lcf = 0.0;
  if (winner){
    const float* cbase = outp + (((size_t)b*NANC + bn)*CHC)*NPIX + gj0*NWW + gi0;
    float sx = 0.0f, sy = 0.0f;
#pragma unroll
    for (int k = 0; k < KK; ++k){
      float rx = cbase[(2*k)*NPIX], ry = cbase[(2*k+1)*NPIX];
      if (k == 0){ rx = sigmoidf_(rx); ry = sigmoidf_(ry); }
      float dx = rx - txv[k], dy = ry - tyv[k];
      sx = fmaf(dx, dx, sx); sy = fmaf(dy, dy, sy);
    }
    lx = 0.5*(double)sx; ly = 0.5*(double)sy;

    // class CE (log_softmax over 13 logits)
    float lg[NCLS], mx = -1e30f;
#pragma unroll
    for (int c = 0; c < NCLS; ++c){ lg[c] = cbase[(2*KK+1+c)*NPIX]; mx = fmaxf(mx, lg[c]); }
    float se = 0.0f;
#pragma unroll
    for (int c = 0; c < NCLS; ++c) se += fast_exp2((lg[c]-mx)*LOG2E_F);
    int label = min(max((int)tcls, 0), NCLS-1);
    lcls = (double)(mx + logf(se) - lg[label]);

    // conf-loss correction at object cell: + 0.5*OBJ*(conf-conf_t)^2 - base term
    float cf = sigmoidf_(cbase[(2*KK)*NPIX]);
    int m0 = mask[(size_t)b*NANCHT + (size_t)bn*NPIX + gj0*NWW + gi0];
    float dcf = cf - conf_t;
    lcf = 0.5*OBJ_W*(double)(dcf*dcf) - (m0 ? 0.5*(double)(cf*cf) : 0.0);
  }

  // single-wave block: shfl reduce doubles, write per-batch partials
#pragma unroll
  for (int o = 32; o > 0; o >>= 1){
    lx  += __shfl_xor(lx,  o, 64);
    ly  += __shfl_xor(ly,  o, 64);
    lcls+= __shfl_xor(lcls,o, 64);
    lcf += __shfl_xor(lcf, o, 64);
  }
  if (threadIdx.x == 0){
    double* bp = bc_part + (size_t)b*4;
    bp[0] = lx; bp[1] = ly; bp[2] = lcls; bp[3] = lcf;
  }
}

// ---------------- finalize: deterministic reduce + epoch gate ----------------
__global__ __launch_bounds__(256) void finalize_kernel(
    const double* __restrict__ bc_part, const double* __restrict__ partials,
    const int* __restrict__ epoch_p, float* __restrict__ outv){
  int tid = threadIdx.x;
  double vx=0, vy=0, vc=0, vf=0, vb=0;
  for (int i = tid; i < NBB; i += 256){
    vx += bc_part[4*i]; vy += bc_part[4*i+1];
    vc += bc_part[4*i+2]; vf += bc_part[4*i+3];
  }
  for (int i = tid; i < 14*NBB; i += 256) vb += partials[i];
#pragma unroll
  for (int o = 32; o > 0; o >>= 1){
    vx += __shfl_xor(vx, o, 64); vy += __shfl_xor(vy, o, 64);
    vc += __shfl_xor(vc, o, 64); vf += __shfl_xor(vf, o, 64);
    vb += __shfl_xor(vb, o, 64);
  }
  __shared__ double sm[5][4];
  int wid = tid >> 6, lane = tid & 63;
  if (lane == 0){ sm[0][wid]=vx; sm[1][wid]=vy; sm[2][wid]=vc; sm[3][wid]=vf; sm[4][wid]=vb; }
  __syncthreads();
  if (tid == 0){
    double fx=0, fy=0, fc=0, ff=0, fb=0;
    for (int w = 0; w < 4; ++w){ fx+=sm[0][w]; fy+=sm[1][w]; fc+=sm[2][w]; ff+=sm[3][w]; fb+=sm[4][w]; }
    double loss = fx + fy + fc;
    if (*epoch_p > EPOCH_PRETRAIN) loss += ff + fb;
    outv[0] = (float)loss;
  }
}

extern "C" void kernel_launch(void* const* d_in, const int* in_sizes, int n_in,
                              void* d_out, int out_size, void* d_ws, size_t ws_size,
                              hipStream_t stream){
  (void)in_sizes; (void)n_in; (void)out_size; (void)ws_size;
  const float* outp = (const float*)d_in[0];
  const float* tgt  = (const float*)d_in[1];
  const int*   ep   = (const int*)d_in[2];
  float* outv = (float*)d_out;
  char* ws = (char*)d_ws;

  double* bc_part  = (double*)(ws);                 // 4096 B
  double* partials = (double*)(ws + 4096);          // 14336 B
  float*  gts_neg  = (float*) (ws + 18432);         // 460800 B
  int*    nvalid   = (int*)   (ws + 479232);        // 512 B
  unsigned char* mask = (unsigned char*)(ws + 479744); // 432640 B

  prep_kernel<<<dim3(NBB), dim3(64), 0, stream>>>(tgt, gts_neg, nvalid);
  region_confmask_kernel<<<dim3(14, NBB), dim3(256), 0, stream>>>(outp, gts_neg, nvalid, mask, partials);
  scatter_loss_kernel<<<dim3(NBB), dim3(64), 0, stream>>>(outp, tgt, nvalid, mask, bc_part);
  finalize_kernel<<<dim3(1), dim3(256), 0, stream>>>(bc_part, partials, ep, outv);
}

// Round 3
// 135.536 us; speedup vs baseline: 1.2576x; 1.0521x over previous
//
#include <hip/hip_runtime.h>
#include <math.h>

// ---------------- problem constants ----------------
#define KK     9     // corners
#define NCLS   13
#define NANC   5     // anchors
#define NBB    128
#define NHH    26
#define NWW    26
#define NTT    50    // targets
#define LL     21    // 2K+3
#define CHC    32    // 2K+1+NC channels per anchor
#define NPIX   676   // NH*NW
#define NANCHT 3380  // NA*NPIX
#define NCELLT 432640 // NB*NANCHT
#define GTS    20    // floats per target in packed gt layout
#define MWPB   106   // mask words per batch (ceil(3380/32) padded)

// derived float constants (computed in double, rounded once)
#define LOG2E_F   1.4426950408889634f
#define K1C       2.8853900817779268f   // SHARP*log2e
#define K2C       0.036067376022224085f // K1C/TH
#define SXW       24.615384615384617f   // 640/26
#define SYH       18.461538461538463f   // 480/26
#define THRESH_S  43.500902934225507f   // 9 + SIL*9*(e^2-1)
#define CULL_T2   292.0f                // > d*^2 = 288.25 where 9*e(d*) == THRESH_S
#define CONF_T_SCALE 0.017390849194407297f // (1/(e^2-1))/9
#define OBJ_W     5.0f
#define EPOCH_PRETRAIN 15
#define BIGV      6.0e18f               // pad sentinel: fma(BIG,BIG,BIG*BIG)=7.2e37 < FLT_MAX

typedef __attribute__((ext_vector_type(2))) float f2;

static __device__ __forceinline__ float fast_exp2(float x){
  return __builtin_amdgcn_exp2f(x);
}
static __device__ __forceinline__ float fast_sqrt(float x){
  return __builtin_amdgcn_sqrtf(x);
}
static __device__ __forceinline__ float sigmoidf_(float x){
  return 1.0f/(1.0f + fast_exp2(-LOG2E_F*x));
}

__constant__ float c_anch[10] = {1.482f,2.2412f,2.0501f,3.1265f,2.3946f,4.6891f,
                                 3.1018f,3.991f,3.4879f,5.8851f};

// ws layout (bytes):
//   [0,4096)         : bc_part  double[NBB][4]
//   [4096,18432)     : partials double[1792]
//   [18432,530432)   : gts_neg  float[NBB*NTT*GTS]  packed NEGATED px corners:
//                        per (b,t): [x0..x8, BIG, y0..y8, BIG]
//   [530432,530944)  : nvalid   int[NBB]
//   [530944,585216)  : maskw    u32[NBB*MWPB]       bit-packed conf_mask0

// ---------------- phase 0: prep (ballot nv; packed negated gt corners) ----------------
__global__ __launch_bounds__(64) void prep_kernel(const float* __restrict__ tgt,
                                                  float* __restrict__ gts_neg,
                                                  int* __restrict__ nvalid){
  int b = blockIdx.x;
  int t = threadIdx.x;                          // one wave
  const float* trow = tgt + (size_t)b*NTT*LL;
  float v1 = (t < NTT) ? trow[t*LL + 1] : 0.0f;
  unsigned long long mk = __ballot(t < NTT && v1 != 0.0f);
  int firstInvalid = __ffsll(~mk) - 1;          // prefix length (cumprod semantics)
  if (t == 0) nvalid[b] = firstInvalid;
  for (int idx = t; idx < NTT*GTS; idx += 64){
    int tt = idx / GTS;
    int c  = idx - tt*GTS;
    float v;
    if (c == 9 || c == 19)      v = BIGV;
    else if (c < 9)             v = -(trow[tt*LL + 1 + 2*c] * 640.0f);
    else                        v = -(trow[tt*LL + 2 + 2*(c-10)] * 480.0f);
    gts_neg[(size_t)b*NTT*GTS + idx] = v;
  }
}

// ---------------- phase A: mask0 via packed cull + rare exact path ----------------
__global__ __launch_bounds__(256) void region_confmask_kernel(
    const float* __restrict__ outp, const float* __restrict__ gts_neg,
    const int* __restrict__ nvalid, unsigned int* __restrict__ maskw,
    double* __restrict__ partials){
  int b = blockIdx.y;
  int cell = blockIdx.x * blockDim.x + threadIdx.x;   // 0..3379 within batch

  __shared__ float sgt[NTT*GTS] __attribute__((aligned(16)));   // 4000 B
  for (int idx = threadIdx.x; idx < NTT*GTS; idx += 256)
    sgt[idx] = gts_neg[(size_t)b*NTT*GTS + idx];
  __syncthreads();

  int m0 = 1;
  float contrib = 0.0f;
  if (cell < NANCHT){
    int a   = cell / NPIX;
    int rem = cell - a*NPIX;
    int j   = rem / NWW;
    int i   = rem - j*NWW;
    const float* base = outp + (((size_t)b*NANC + a)*CHC)*NPIX + rem;

    f2 Pxp[5], Pyp[5];
#pragma unroll
    for (int k = 0; k < KK; ++k){
      float rx = base[(2*k)*NPIX];
      float ry = base[(2*k+1)*NPIX];
      if (k == 0){ rx = sigmoidf_(rx); ry = sigmoidf_(ry); }
      Pxp[k>>1][k&1] = (rx + (float)i) * SXW;
      Pyp[k>>1][k&1] = (ry + (float)j) * SYH;
    }
    Pxp[4][1] = 0.0f; Pyp[4][1] = 0.0f;          // pad corner vs BIG sentinel

    int nv = nvalid[b];                           // wave-uniform
    unsigned long long qbits = 0ull;
#pragma unroll 2
    for (int t = 0; t < nv; ++t){
      const f2* gx = (const f2*)(sgt + t*GTS);    // 5 packed x pairs
      const f2* gy = gx + 5;                      // 5 packed y pairs
      f2 m2 = {1e30f, 1e30f};
#pragma unroll
      for (int p = 0; p < 5; ++p){
        f2 dx = Pxp[p] + gx[p];                   // v_pk_add_f32 (gt pre-negated)
        f2 dy = Pyp[p] + gy[p];
        f2 r  = __builtin_elementwise_fma(dy, dy, dx*dx);  // pk_mul + pk_fma
        m2 = __builtin_elementwise_min(m2, r);
      }
      if (fminf(m2.x, m2.y) < CULL_T2) qbits |= (1ull << t);
    }

    if (__any(qbits != 0ull)){                    // exact path for near pairs
      bool exc = false;
      while (qbits){
        int t = __ffsll((long long)qbits) - 1;
        qbits &= qbits - 1;
        const float* gg = sgt + t*GTS;
        float s = 0.0f;
#pragma unroll
        for (int k = 0; k < KK; ++k){
          float dx = Pxp[k>>1][k&1] + gg[k];
          float dy = Pyp[k>>1][k&1] + gg[10+k];
          float d  = fast_sqrt(fmaf(dy, dy, dx*dx));   // identical to R0 math
          float e  = fast_exp2(fmaf(d, -K2C, K1C));
          s += fmaxf(e, 1.0f);
        }
        exc |= (s > THRESH_S);
      }
      if (exc) m0 = 0;
    }
    float cf = sigmoidf_(base[(2*KK)*NPIX]);
    contrib = m0 ? 0.5f*cf*cf : 0.0f;
  }

  // bit-packed mask write: one ballot per wave, two u32 stores
  unsigned long long mb = __ballot(m0 != 0);
  int lane = threadIdx.x & 63;
  int wavebase = blockIdx.x * 256 + (threadIdx.x & ~63);   // 64-aligned within batch
  if ((lane & 31) == 0 && wavebase < NANCHT){
    unsigned int w = (lane == 0) ? (unsigned int)mb : (unsigned int)(mb >> 32);
    maskw[(size_t)b*MWPB + (wavebase >> 5) + (lane >> 5)] = w;
  }

  // block reduce -> one double partial per block (deterministic, no atomics)
#pragma unroll
  for (int o = 32; o > 0; o >>= 1) contrib += __shfl_xor(contrib, o, 64);
  __shared__ float wsum[4];
  int wid = threadIdx.x >> 6;
  if (lane == 0) wsum[wid] = contrib;
  __syncthreads();
  if (threadIdx.x == 0){
    double tot = (double)wsum[0] + (double)wsum[1] + (double)wsum[2] + (double)wsum[3];
    partials[blockIdx.y * gridDim.x + blockIdx.x] = tot;
  }
}

// ---------------- phase B+C: per-target values, scatter winners, small losses ----------------
__global__ __launch_bounds__(64) void scatter_loss_kernel(
    const float* __restrict__ outp, const float* __restrict__ tgt,
    const int* __restrict__ nvalid, const unsigned int* __restrict__ maskw,
    double* __restrict__ bc_part){
  int b = blockIdx.x;
  int t = threadIdx.x;                  // 0..63, targets are 0..49
  __shared__ int keys[NTT];
  int nv = nvalid[b];
  bool valid = (t < nv);

  int key = -1, gi0 = 0, gj0 = 0, bn = 0;
  float txv[KK], tyv[KK];
  float conf_t = 0.0f, tcls = 0.0f;

  if (t < NTT){
    const float* trow = tgt + ((size_t)b*NTT + t)*LL;
    tcls = trow[0];
    float gx0 = trow[1]*(float)NWW;
    float gy0 = trow[2]*(float)NHH;
    gi0 = min(max((int)floorf(gx0), 0), NWW-1);
    gj0 = min(max((int)floorf(gy0), 0), NHH-1);
#pragma unroll
    for (int k = 0; k < KK; ++k){
      txv[k] = trow[1+2*k]*(float)NWW - (float)gi0;
      tyv[k] = trow[2+2*k]*(float)NHH - (float)gj0;
    }
    // best anchor by IoU (first max wins)
    float gw = trow[LL-2]*(float)NWW, gh = trow[LL-1]*(float)NHH;
    float best = -1.0f;
    for (int a = 0; a < NANC; ++a){
      float aw = c_anch[2*a], ah = c_anch[2*a+1];
      float inter = fminf(aw, gw) * fminf(ah, gh);
      float iou = inter / (aw*ah + gw*gh - inter);
      if (iou > best){ best = iou; bn = a; }
    }
    key = bn*NPIX + gj0*NWW + gi0;
    keys[t] = key;

    // conf_t from pred_box at the wrapped flat index (reference's mod arithmetic)
    long f = (long)b*NANCHT - NPIX + gj0*NWW + gi0;
    if (f < 0) f += NCELLT;
    int bb  = (int)(f / NANCHT);
    int rr  = (int)(f - (long)bb*NANCHT);
    int aa  = rr / NPIX;
    int rr2 = rr - aa*NPIX;
    int jj  = rr2 / NWW;
    int ii  = rr2 - jj*NWW;
    const float* pbase = outp + (((size_t)bb*NANC + aa)*CHC)*NPIX + rr2;
    float s = 0.0f;
#pragma unroll
    for (int k = 0; k < KK; ++k){
      float rx = pbase[(2*k)*NPIX], ry = pbase[(2*k+1)*NPIX];
      if (k == 0){ rx = sigmoidf_(rx); ry = sigmoidf_(ry); }
      float Pxx = (rx + (float)ii)*SXW, Pyy = (ry + (float)jj)*SYH;
      float dx = Pxx - trow[1+2*k]*640.0f;
      float dy = Pyy - trow[2+2*k]*480.0f;
      float d  = fast_sqrt(fmaf(dy, dy, dx*dx));
      float e  = fast_exp2(fmaf(d, -K2C, K1C));
      s += fmaxf(e, 1.0f);
    }
    conf_t = (s - 9.0f) * CONF_T_SCALE;
  }
  __syncthreads();

  // winner = last valid t writing this (bn,gj,gi) cell (scan overwrite semantics)
  bool winner = valid;
  if (valid){
    for (int u = t+1; u < nv; ++u) if (keys[u] == key){ winner = false; break; }
  }

  double lx = 0.0, ly = 0.0, lcls = 0.0, lcf = 0.0;
  if (winner){
    const float* cbase = outp + (((size_t)b*NANC + bn)*CHC)*NPIX + gj0*NWW + gi0;
    float sx = 0.0f, sy = 0.0f;
#pragma unroll
    for (int k = 0; k < KK; ++k){
      float rx = cbase[(2*k)*NPIX], ry = cbase[(2*k+1)*NPIX];
      if (k == 0){ rx = sigmoidf_(rx); ry = sigmoidf_(ry); }
      float dx = rx - txv[k], dy = ry - tyv[k];
      sx = fmaf(dx, dx, sx); sy = fmaf(dy, dy, sy);
    }
    lx = 0.5*(double)sx; ly = 0.5*(double)sy;

    // class CE (log_softmax over 13 logits)
    float lg[NCLS], mx = -1e30f;
#pragma unroll
    for (int c = 0; c < NCLS; ++c){ lg[c] = cbase[(2*KK+1+c)*NPIX]; mx = fmaxf(mx, lg[c]); }
    float se = 0.0f;
#pragma unroll
    for (int c = 0; c < NCLS; ++c) se += fast_exp2((lg[c]-mx)*LOG2E_F);
    int label = min(max((int)tcls, 0), NCLS-1);
    lcls = (double)(mx + logf(se) - lg[label]);

    // conf-loss correction at object cell: + 0.5*OBJ*(conf-conf_t)^2 - base term
    float cf = sigmoidf_(cbase[(2*KK)*NPIX]);
    int idx = bn*NPIX + gj0*NWW + gi0;
    int m0 = (maskw[(size_t)b*MWPB + (idx >> 5)] >> (idx & 31)) & 1;
    float dcf = cf - conf_t;
    lcf = 0.5*OBJ_W*(double)(dcf*dcf) - (m0 ? 0.5*(double)(cf*cf) : 0.0);
  }

  // single-wave block: shfl reduce doubles, write per-batch partials
#pragma unroll
  for (int o = 32; o > 0; o >>= 1){
    lx  += __shfl_xor(lx,  o, 64);
    ly  += __shfl_xor(ly,  o, 64);
    lcls+= __shfl_xor(lcls,o, 64);
    lcf += __shfl_xor(lcf, o, 64);
  }
  if (threadIdx.x == 0){
    double* bp = bc_part + (size_t)b*4;
    bp[0] = lx; bp[1] = ly; bp[2] = lcls; bp[3] = lcf;
  }
}

// ---------------- finalize: deterministic reduce + epoch gate ----------------
__global__ __launch_bounds__(256) void finalize_kernel(
    const double* __restrict__ bc_part, const double* __restrict__ partials,
    const int* __restrict__ epoch_p, float* __restrict__ outv){
  int tid = threadIdx.x;
  double vx=0, vy=0, vc=0, vf=0, vb=0;
  for (int i = tid; i < NBB; i += 256){
    vx += bc_part[4*i]; vy += bc_part[4*i+1];
    vc += bc_part[4*i+2]; vf += bc_part[4*i+3];
  }
  for (int i = tid; i < 14*NBB; i += 256) vb += partials[i];
#pragma unroll
  for (int o = 32; o > 0; o >>= 1){
    vx += __shfl_xor(vx, o, 64); vy += __shfl_xor(vy, o, 64);
    vc += __shfl_xor(vc, o, 64); vf += __shfl_xor(vf, o, 64);
    vb += __shfl_xor(vb, o, 64);
  }
  __shared__ double sm[5][4];
  int wid = tid >> 6, lane = tid & 63;
  if (lane == 0){ sm[0][wid]=vx; sm[1][wid]=vy; sm[2][wid]=vc; sm[3][wid]=vf; sm[4][wid]=vb; }
  __syncthreads();
  if (tid == 0){
    double fx=0, fy=0, fc=0, ff=0, fb=0;
    for (int w = 0; w < 4; ++w){ fx+=sm[0][w]; fy+=sm[1][w]; fc+=sm[2][w]; ff+=sm[3][w]; fb+=sm[4][w]; }
    double loss = fx + fy + fc;
    if (*epoch_p > EPOCH_PRETRAIN) loss += ff + fb;
    outv[0] = (float)loss;
  }
}

extern "C" void kernel_launch(void* const* d_in, const int* in_sizes, int n_in,
                              void* d_out, int out_size, void* d_ws, size_t ws_size,
                              hipStream_t stream){
  (void)in_sizes; (void)n_in; (void)out_size; (void)ws_size;
  const float* outp = (const float*)d_in[0];
  const float* tgt  = (const float*)d_in[1];
  const int*   ep   = (const int*)d_in[2];
  float* outv = (float*)d_out;
  char* ws = (char*)d_ws;

  double* bc_part  = (double*)(ws);                  // 4096 B
  double* partials = (double*)(ws + 4096);           // 14336 B
  float*  gts_neg  = (float*) (ws + 18432);          // 512000 B
  int*    nvalid   = (int*)   (ws + 530432);         // 512 B
  unsigned int* maskw = (unsigned int*)(ws + 530944); // 54272 B

  prep_kernel<<<dim3(NBB), dim3(64), 0, stream>>>(tgt, gts_neg, nvalid);
  region_confmask_kernel<<<dim3(14, NBB), dim3(256), 0, stream>>>(outp, gts_neg, nvalid, maskw, partials);
  scatter_loss_kernel<<<dim3(NBB), dim3(64), 0, stream>>>(outp, tgt, nvalid, maskw, bc_part);
  finalize_kernel<<<dim3(1), dim3(256), 0, stream>>>(bc_part, partials, ep, outv);
}